// Round 16
// baseline (530.240 us; speedup 1.0000x reference)
//
#include <hip/hip_runtime.h>
#include <math.h>

#define SCALE_Q 0.17677669529663687f

typedef __attribute__((ext_vector_type(8))) short bf16x8;
typedef __attribute__((ext_vector_type(4))) float f32x4;
typedef __attribute__((ext_vector_type(4))) unsigned short u16x4;

static __device__ __forceinline__ unsigned short f2bf(float f) {
    unsigned int u = __float_as_uint(f);
    u += 0x7FFF + ((u >> 16) & 1);
    return (unsigned short)(u >> 16);
}

// fast GELU: v * sigmoid(2s), s = sqrt(2/pi)*(v + 0.044715 v^3); |err| < ~1e-3
static __device__ __forceinline__ float gelu_fast(float v) {
    float s = v * (0.7978845608f + 0.0356774081f * v * v);
    float e = __expf(-2.0f * s);
    return v * __builtin_amdgcn_rcpf(1.0f + e);
}

// ---------------------------------------------------------------------------
// Prep: weights f32 -> bf16 in ws; padded attention bias 8 x 64 x 64
// ---------------------------------------------------------------------------
__global__ void prep_kernel(const float* __restrict__ qkv_w, const float* __restrict__ proj_w,
                            const float* __restrict__ fc1_w, const float* __restrict__ fc2_w,
                            const float* __restrict__ bias_table, const int* __restrict__ rel_index,
                            unsigned short* __restrict__ wq, unsigned short* __restrict__ wp,
                            unsigned short* __restrict__ w1, unsigned short* __restrict__ w2,
                            float* __restrict__ bias_pad) {
    int tid = blockIdx.x * blockDim.x + threadIdx.x;
    int stride = gridDim.x * blockDim.x;
    for (int i = tid; i < 768 * 256; i += stride) wq[i] = f2bf(qkv_w[i]);
    for (int i = tid; i < 256 * 256; i += stride) wp[i] = f2bf(proj_w[i]);
    for (int i = tid; i < 1024 * 256; i += stride) w1[i] = f2bf(fc1_w[i]);
    for (int i = tid; i < 256 * 1024; i += stride) w2[i] = f2bf(fc2_w[i]);
    for (int i = tid; i < 8 * 64 * 64; i += stride) {
        int h = i >> 12, q = (i >> 6) & 63, k = i & 63;
        float v;
        if (k >= 50) v = -1e30f;
        else if (q == 0 || k == 0 || q >= 50) v = 0.f;
        else v = bias_table[rel_index[(q - 1) * 49 + (k - 1)] * 8 + h];
        bias_pad[i] = v;
    }
}

// ---------------------------------------------------------------------------
// Fused attention block, 1024 threads = 16 waves, one window per block.
// (round-9 bench form — global best; unchanged)
// ---------------------------------------------------------------------------
template <int IS_RSA>
__global__ __launch_bounds__(1024, 4) void attn_kernel(
    const float* __restrict__ reg_tok, const float* __restrict__ x,
    const float* __restrict__ reg2_in, float* __restrict__ out,
    const float* __restrict__ ln_g, const float* __restrict__ ln_b,
    const unsigned short* __restrict__ wq, const float* __restrict__ qkv_b,
    const unsigned short* __restrict__ wp, const float* __restrict__ proj_b,
    const float* __restrict__ bias_pad) {
    __shared__ __align__(16) unsigned char smem[140288];
    unsigned short* regA = (unsigned short*)smem;             // xln / attn_out
    unsigned short* regB = (unsigned short*)(smem + 36864);   // q|k rows
    unsigned short* vT   = (unsigned short*)(smem + 103424);  // 256 x 72

    const int tid = threadIdx.x;
    const int lane = tid & 63;
    const int wid = tid >> 6;          // 0..15
    const int l15 = lane & 15;
    const int lg = lane >> 4;
    const int u = blockIdx.x;
    const int NV = IS_RSA ? 64 : 50;
    const f32x4 fzero = {0.f, 0.f, 0.f, 0.f};

    int reg_off = 0, xb = 0, wi = 0, wj = 0;
    if (!IS_RSA) {
        reg_off = ((u & 31) * 64 + (u >> 5)) * 256;
        xb = u >> 6;
        int xn = u & 63;
        wi = xn >> 3; wj = xn & 7;
    }

    // ---- phase 1: gather + layernorm -> regA bf16 (zero the pad rows) ----
    for (int r = wid; r < 64; r += 16) {
        if (r < NV) {
            const float* src;
            if (IS_RSA) src = reg_tok + (u * 64 + r) * 256;
            else if (r == 0) src = reg2_in + reg_off;
            else {
                int p = r - 1;
                src = x + (xb * 3136 + (wi * 7 + p / 7) * 56 + (wj * 7 + p % 7)) * 256;
            }
            f32x4 v = *(const f32x4*)(src + lane * 4);
            float s = v[0] + v[1] + v[2] + v[3];
            float s2 = v[0] * v[0] + v[1] * v[1] + v[2] * v[2] + v[3] * v[3];
            #pragma unroll
            for (int m = 1; m < 64; m <<= 1) { s += __shfl_xor(s, m); s2 += __shfl_xor(s2, m); }
            float mean = s * 0.00390625f;
            float rstd = rsqrtf(s2 * 0.00390625f - mean * mean + 1e-5f);
            u16x4 o;
            #pragma unroll
            for (int j = 0; j < 4; ++j) {
                int c = lane * 4 + j;
                o[j] = f2bf((v[j] - mean) * rstd * ln_g[c] + ln_b[c]);
            }
            *(u16x4*)(regA + r * 264 + lane * 4) = o;
        } else {
            u16x4 z = {0, 0, 0, 0};
            *(u16x4*)(regA + r * 264 + lane * 4) = z;
        }
    }
    __syncthreads();

    const int h = wid >> 1;
    const int qb = (wid & 1) * 32;

    // ---- phase 2: qkv = xln @ wq^T + b; q,k -> regB rows; v -> vT transposed ----
    {
        f32x4 acc[4][3];
        #pragma unroll
        for (int mi = 0; mi < 4; ++mi)
            #pragma unroll
            for (int t = 0; t < 3; ++t) acc[mi][t] = fzero;
        #pragma unroll
        for (int ks = 0; ks < 8; ++ks) {
            int k = ks * 32 + lg * 8;
            bf16x8 a[4], b[3];
            #pragma unroll
            for (int mi = 0; mi < 4; ++mi) a[mi] = *(const bf16x8*)(regA + (mi * 16 + l15) * 264 + k);
            #pragma unroll
            for (int t = 0; t < 3; ++t) b[t] = *(const bf16x8*)(wq + (wid * 48 + t * 16 + l15) * 256 + k);
            #pragma unroll
            for (int mi = 0; mi < 4; ++mi)
                #pragma unroll
                for (int t = 0; t < 3; ++t)
                    acc[mi][t] = __builtin_amdgcn_mfma_f32_16x16x32_bf16(a[mi], b[t], acc[mi][t], 0, 0, 0);
        }
        #pragma unroll
        for (int mi = 0; mi < 4; ++mi)
            #pragma unroll
            for (int t = 0; t < 3; ++t) {
                int col = wid * 48 + t * 16 + l15;
                float bias = qkv_b[col];
                #pragma unroll
                for (int r = 0; r < 4; ++r) {
                    int row = mi * 16 + lg * 4 + r;
                    unsigned short hv = f2bf(acc[mi][t][r] + bias);
                    if (col < 512) regB[row * 520 + col] = hv;
                    else vT[(col - 512) * 72 + row] = hv;
                }
            }
    }

    // prefetch relative-position bias (8 x f32x4) before the barrier
    f32x4 bv[4][2];
    if (!IS_RSA) {
        #pragma unroll
        for (int mi = 0; mi < 4; ++mi)
            #pragma unroll
            for (int nj = 0; nj < 2; ++nj)
                bv[mi][nj] = *(const f32x4*)(bias_pad + h * 4096 + (qb + nj * 16 + l15) * 64 + mi * 16 + lg * 4);
    }
    __syncthreads();

    // ---- phase 3: swapped attention. S^T[k][q] = sum_d K[k][d] Q[q][d] ----
    f32x4 st[4][2];
    {
        int k0 = h * 32 + lg * 8;
        bf16x8 af[4], bfq[2];
        #pragma unroll
        for (int mi = 0; mi < 4; ++mi) af[mi] = *(const bf16x8*)(regB + (mi * 16 + l15) * 520 + 256 + k0);
        #pragma unroll
        for (int nj = 0; nj < 2; ++nj) bfq[nj] = *(const bf16x8*)(regB + (qb + nj * 16 + l15) * 520 + k0);
        #pragma unroll
        for (int mi = 0; mi < 4; ++mi)
            #pragma unroll
            for (int nj = 0; nj < 2; ++nj)
                st[mi][nj] = __builtin_amdgcn_mfma_f32_16x16x32_bf16(af[mi], bfq[nj], fzero, 0, 0, 0);
    }

    // softmax over k (rows of S^T); lane l15 = q-col, k spread over (mi, lg, r)
    u16x4 pf[4][2];  // packed bf16 P^T fragment (low 4 k-slots)
    #pragma unroll
    for (int nj = 0; nj < 2; ++nj) {
        float ps[4][4];
        float mx = -3.0e38f;
        #pragma unroll
        for (int mi = 0; mi < 4; ++mi)
            #pragma unroll
            for (int r = 0; r < 4; ++r) {
                float t = st[mi][nj][r] * SCALE_Q;
                if (!IS_RSA) t += bv[mi][nj][r];
                ps[mi][r] = t;
                mx = fmaxf(mx, t);
            }
        mx = fmaxf(mx, __shfl_xor(mx, 16));
        mx = fmaxf(mx, __shfl_xor(mx, 32));
        float sum = 0.f;
        #pragma unroll
        for (int mi = 0; mi < 4; ++mi)
            #pragma unroll
            for (int r = 0; r < 4; ++r) { ps[mi][r] = __expf(ps[mi][r] - mx); sum += ps[mi][r]; }
        sum += __shfl_xor(sum, 16);
        sum += __shfl_xor(sum, 32);
        float inv = __builtin_amdgcn_rcpf(sum);
        #pragma unroll
        for (int mi = 0; mi < 4; ++mi) {
            u16x4 p4;
            #pragma unroll
            for (int r = 0; r < 4; ++r) p4[r] = f2bf(ps[mi][r] * inv);
            pf[mi][nj] = p4;
        }
    }

    // PV via K=16-emulated 16x16x32 MFMA: O^T[d][q] += V^T-frag * P^T-frag
    f32x4 ov[2][2];
    #pragma unroll
    for (int m2 = 0; m2 < 2; ++m2) { ov[m2][0] = fzero; ov[m2][1] = fzero; }
    #pragma unroll
    for (int kt = 0; kt < 4; ++kt) {
        bf16x8 pb[2];
        #pragma unroll
        for (int nj = 0; nj < 2; ++nj) {
            bf16x8 t;
            t[0] = (short)pf[kt][nj][0]; t[1] = (short)pf[kt][nj][1];
            t[2] = (short)pf[kt][nj][2]; t[3] = (short)pf[kt][nj][3];
            t[4] = 0; t[5] = 0; t[6] = 0; t[7] = 0;
            pb[nj] = t;
        }
        #pragma unroll
        for (int m2 = 0; m2 < 2; ++m2) {
            u16x4 av = *(const u16x4*)(vT + (h * 32 + m2 * 16 + l15) * 72 + kt * 16 + lg * 4);
            bf16x8 a8;
            a8[0] = (short)av[0]; a8[1] = (short)av[1]; a8[2] = (short)av[2]; a8[3] = (short)av[3];
            a8[4] = 0; a8[5] = 0; a8[6] = 0; a8[7] = 0;
            #pragma unroll
            for (int nj = 0; nj < 2; ++nj)
                ov[m2][nj] = __builtin_amdgcn_mfma_f32_16x16x32_bf16(a8, pb[nj], ov[m2][nj], 0, 0, 0);
        }
    }
    // attn_out: row q = qb+nj*16+l15, cols h*32+m2*16+lg*4+r -> vector u16x4
    #pragma unroll
    for (int m2 = 0; m2 < 2; ++m2)
        #pragma unroll
        for (int nj = 0; nj < 2; ++nj) {
            u16x4 o4;
            #pragma unroll
            for (int r = 0; r < 4; ++r) o4[r] = f2bf(ov[m2][nj][r]);
            *(u16x4*)(regA + (qb + nj * 16 + l15) * 264 + h * 32 + m2 * 16 + lg * 4) = o4;
        }
    __syncthreads();

    // ---- phase 4: proj + bias + residual, scatter to destination ----
    {
        int nb = wid * 16;
        f32x4 acc[4];
        #pragma unroll
        for (int mi = 0; mi < 4; ++mi) acc[mi] = fzero;
        #pragma unroll
        for (int ks = 0; ks < 8; ++ks) {
            int k = ks * 32 + lg * 8;
            bf16x8 a[4], b;
            #pragma unroll
            for (int mi = 0; mi < 4; ++mi) a[mi] = *(const bf16x8*)(regA + (mi * 16 + l15) * 264 + k);
            b = *(const bf16x8*)(wp + (nb + l15) * 256 + k);
            #pragma unroll
            for (int mi = 0; mi < 4; ++mi)
                acc[mi] = __builtin_amdgcn_mfma_f32_16x16x32_bf16(a[mi], b, acc[mi], 0, 0, 0);
        }
        int col = nb + l15;
        float pb = proj_b[col];
        #pragma unroll
        for (int mi = 0; mi < 4; ++mi)
            #pragma unroll
            for (int r = 0; r < 4; ++r) {
                int row = mi * 16 + lg * 4 + r;
                if (row < NV) {
                    float val = acc[mi][r] + pb;
                    if (IS_RSA) {
                        int off = (u * 64 + row) * 256 + col;
                        out[off] = val + reg_tok[off];
                    } else if (row == 0) {
                        out[reg_off + col] = val + reg2_in[reg_off + col];
                    } else {
                        int p = row - 1;
                        int off = (xb * 3136 + (wi * 7 + p / 7) * 56 + (wj * 7 + p % 7)) * 256 + col;
                        out[524288 + off] = val + x[off];
                    }
                }
            }
    }
}

// ---------------------------------------------------------------------------
// Fused MLP over the dense t-matrix (d_out): 64 rows / 512 threads (8 waves).
// r9 structure with 256-hidden chunks (4 chunks): wave owns 32 hidden cols in
// fc1 -> the xst A-fragments are reused for 2 b-frags, HALVING fc1 LDS reads
// (256 -> 128 b128/wave) at UNCHANGED global weight loads (64+64/wave).
// hld single-buffered 64x264; 2 barriers/chunk x 4 = 8 (same total as r9).
// LDS 67.6 KB -> 2 blocks/CU.
// ---------------------------------------------------------------------------
__global__ __launch_bounds__(512, 4) void mlp_kernel(
    float* __restrict__ dout,
    const float* __restrict__ ln_g, const float* __restrict__ ln_b,
    const unsigned short* __restrict__ w1, const float* __restrict__ b1,
    const unsigned short* __restrict__ w2, const float* __restrict__ b2) {
    __shared__ __align__(16) unsigned short xst[64 * 264];
    __shared__ __align__(16) unsigned short hld[64 * 264];
    const int tid = threadIdx.x;
    const int lane = tid & 63;
    const int wid = tid >> 6;          // 0..7
    const int l15 = lane & 15;
    const int lg = lane >> 4;
    const int row0 = blockIdx.x * 64;
    const f32x4 fzero = {0.f, 0.f, 0.f, 0.f};

    // ---- LN: 8 rows per wave -> xst (once) ----
    #pragma unroll
    for (int i = 0; i < 8; ++i) {
        int r = wid * 8 + i;
        f32x4 v = *(const f32x4*)(dout + (row0 + r) * 256 + lane * 4);
        float s = v[0] + v[1] + v[2] + v[3];
        float s2 = v[0] * v[0] + v[1] * v[1] + v[2] * v[2] + v[3] * v[3];
        #pragma unroll
        for (int m = 1; m < 64; m <<= 1) { s += __shfl_xor(s, m); s2 += __shfl_xor(s2, m); }
        float mean = s * 0.00390625f;
        float rstd = rsqrtf(s2 * 0.00390625f - mean * mean + 1e-5f);
        u16x4 o;
        #pragma unroll
        for (int j = 0; j < 4; ++j) {
            int c = lane * 4 + j;
            o[j] = f2bf((v[j] - mean) * rstd * ln_g[c] + ln_b[c]);
        }
        *(u16x4*)(xst + r * 264 + lane * 4) = o;
    }
    __syncthreads();

    f32x4 acc2[4][2];
    #pragma unroll
    for (int mi = 0; mi < 4; ++mi) { acc2[mi][0] = fzero; acc2[mi][1] = fzero; }

    #pragma unroll
    for (int c = 0; c < 4; ++c) {
        // ---- fc1: all 64 rows x this wave's 32 hidden cols (chunk = 256) ----
        f32x4 acc1[4][2];
        #pragma unroll
        for (int mi = 0; mi < 4; ++mi) { acc1[mi][0] = fzero; acc1[mi][1] = fzero; }
        #pragma unroll
        for (int ks = 0; ks < 8; ++ks) {
            int k = ks * 32 + lg * 8;
            bf16x8 a[4], b[2];
            #pragma unroll
            for (int mi = 0; mi < 4; ++mi)
                a[mi] = *(const bf16x8*)(xst + (mi * 16 + l15) * 264 + k);
            #pragma unroll
            for (int ni = 0; ni < 2; ++ni)
                b[ni] = *(const bf16x8*)(w1 + (c * 256 + wid * 32 + ni * 16 + l15) * 256 + k);
            #pragma unroll
            for (int mi = 0; mi < 4; ++mi)
                #pragma unroll
                for (int ni = 0; ni < 2; ++ni)
                    acc1[mi][ni] = __builtin_amdgcn_mfma_f32_16x16x32_bf16(a[mi], b[ni], acc1[mi][ni], 0, 0, 0);
        }
        // ---- GELU -> hld ----
        #pragma unroll
        for (int ni = 0; ni < 2; ++ni) {
            int hc = wid * 32 + ni * 16 + l15;
            float bb = b1[c * 256 + hc];
            #pragma unroll
            for (int mi = 0; mi < 4; ++mi)
                #pragma unroll
                for (int r = 0; r < 4; ++r)
                    hld[(mi * 16 + lg * 4 + r) * 264 + hc] = f2bf(gelu_fast(acc1[mi][ni][r] + bb));
        }
        __syncthreads();  // hld writes visible
        // ---- fc2: K = this chunk's 256 hidden; wave owns 32 out cols ----
        #pragma unroll
        for (int ks = 0; ks < 8; ++ks) {
            int k = ks * 32 + lg * 8;
            bf16x8 a[4], b[2];
            #pragma unroll
            for (int mi = 0; mi < 4; ++mi)
                a[mi] = *(const bf16x8*)(hld + (mi * 16 + l15) * 264 + k);
            #pragma unroll
            for (int ni = 0; ni < 2; ++ni)
                b[ni] = *(const bf16x8*)(w2 + (wid * 32 + ni * 16 + l15) * 1024 + c * 256 + k);
            #pragma unroll
            for (int mi = 0; mi < 4; ++mi)
                #pragma unroll
                for (int ni = 0; ni < 2; ++ni)
                    acc2[mi][ni] = __builtin_amdgcn_mfma_f32_16x16x32_bf16(a[mi], b[ni], acc2[mi][ni], 0, 0, 0);
        }
        __syncthreads();  // hld reads done before next chunk's writes
    }
    #pragma unroll
    for (int mi = 0; mi < 4; ++mi)
        #pragma unroll
        for (int ni = 0; ni < 2; ++ni) {
            int col = wid * 32 + ni * 16 + l15;
            float bb = b2[col];
            #pragma unroll
            for (int r = 0; r < 4; ++r) {
                int row = row0 + mi * 16 + lg * 4 + r;
                float* dst = dout + row * 256 + col;
                *dst = acc2[mi][ni][r] + bb + *dst;
            }
        }
}

// ---------------------------------------------------------------------------
extern "C" void kernel_launch(void* const* d_in, const int* in_sizes, int n_in,
                              void* d_out, int out_size, void* d_ws, size_t ws_size,
                              hipStream_t stream) {
    const float* regional = (const float*)d_in[0];
    const float* x = (const float*)d_in[1];
    const float* n1g = (const float*)d_in[2];
    const float* n1b = (const float*)d_in[3];
    const float* n2g = (const float*)d_in[4];
    const float* n2b = (const float*)d_in[5];
    const float* n3g = (const float*)d_in[6];
    const float* n3b = (const float*)d_in[7];
    const float* qkvw = (const float*)d_in[8];
    const float* qkvb = (const float*)d_in[9];
    const float* projw = (const float*)d_in[10];
    const float* projb = (const float*)d_in[11];
    const float* btab = (const float*)d_in[12];
    const float* f1w = (const float*)d_in[13];
    const float* f1b = (const float*)d_in[14];
    const float* f2w = (const float*)d_in[15];
    const float* f2b = (const float*)d_in[16];
    const int* relidx = (const int*)d_in[17];

    unsigned char* ws = (unsigned char*)d_ws;
    unsigned short* wq = (unsigned short*)(ws);            // 768*256  bf16
    unsigned short* wp = (unsigned short*)(ws + 393216);   // 256*256  bf16
    unsigned short* w1 = (unsigned short*)(ws + 524288);   // 1024*256 bf16
    unsigned short* w2 = (unsigned short*)(ws + 1048576);  // 256*1024 bf16
    float* bias_pad    = (float*)(ws + 1572864);           // 8*64*64 f32
    float* reg2        = (float*)(ws + 1703936);           // 32*64*256 f32

    float* out = (float*)d_out;

    prep_kernel<<<512, 256, 0, stream>>>(qkvw, projw, f1w, f2w, btab, relidx, wq, wp, w1, w2, bias_pad);
    attn_kernel<1><<<32, 1024, 0, stream>>>(regional, x, nullptr, reg2, n1g, n1b, wq, qkvb, wp, projb, nullptr);
    attn_kernel<0><<<2048, 1024, 0, stream>>>(regional, x, reg2, out, n2g, n2b, wq, qkvb, wp, projb, bias_pad);
    mlp_kernel<<<1600, 512, 0, stream>>>(out, n3g, n3b, w1, f1b, w2, f2b);
}

// Round 17
// 484.875 us; speedup vs baseline: 1.0936x; 1.0936x over previous
//
#include <hip/hip_runtime.h>
#include <math.h>

#define SCALE_Q 0.17677669529663687f

typedef __attribute__((ext_vector_type(8))) short bf16x8;
typedef __attribute__((ext_vector_type(4))) float f32x4;
typedef __attribute__((ext_vector_type(4))) unsigned short u16x4;

static __device__ __forceinline__ unsigned short f2bf(float f) {
    unsigned int u = __float_as_uint(f);
    u += 0x7FFF + ((u >> 16) & 1);
    return (unsigned short)(u >> 16);
}

// fast GELU: v * sigmoid(2s), s = sqrt(2/pi)*(v + 0.044715 v^3); |err| < ~1e-3
static __device__ __forceinline__ float gelu_fast(float v) {
    float s = v * (0.7978845608f + 0.0356774081f * v * v);
    float e = __expf(-2.0f * s);
    return v * __builtin_amdgcn_rcpf(1.0f + e);
}

// ---------------------------------------------------------------------------
// Prep: weights f32 -> bf16 in ws; padded attention bias 8 x 64 x 64
// ---------------------------------------------------------------------------
__global__ void prep_kernel(const float* __restrict__ qkv_w, const float* __restrict__ proj_w,
                            const float* __restrict__ fc1_w, const float* __restrict__ fc2_w,
                            const float* __restrict__ bias_table, const int* __restrict__ rel_index,
                            unsigned short* __restrict__ wq, unsigned short* __restrict__ wp,
                            unsigned short* __restrict__ w1, unsigned short* __restrict__ w2,
                            float* __restrict__ bias_pad) {
    int tid = blockIdx.x * blockDim.x + threadIdx.x;
    int stride = gridDim.x * blockDim.x;
    for (int i = tid; i < 768 * 256; i += stride) wq[i] = f2bf(qkv_w[i]);
    for (int i = tid; i < 256 * 256; i += stride) wp[i] = f2bf(proj_w[i]);
    for (int i = tid; i < 1024 * 256; i += stride) w1[i] = f2bf(fc1_w[i]);
    for (int i = tid; i < 256 * 1024; i += stride) w2[i] = f2bf(fc2_w[i]);
    for (int i = tid; i < 8 * 64 * 64; i += stride) {
        int h = i >> 12, q = (i >> 6) & 63, k = i & 63;
        float v;
        if (k >= 50) v = -1e30f;
        else if (q == 0 || k == 0 || q >= 50) v = 0.f;
        else v = bias_table[rel_index[(q - 1) * 49 + (k - 1)] * 8 + h];
        bias_pad[i] = v;
    }
}

// ---------------------------------------------------------------------------
// Fused attention block, 1024 threads = 16 waves, one window per block.
// (round-9 bench form — global best)
// ---------------------------------------------------------------------------
template <int IS_RSA>
__global__ __launch_bounds__(1024, 4) void attn_kernel(
    const float* __restrict__ reg_tok, const float* __restrict__ x,
    const float* __restrict__ reg2_in, float* __restrict__ out,
    const float* __restrict__ ln_g, const float* __restrict__ ln_b,
    const unsigned short* __restrict__ wq, const float* __restrict__ qkv_b,
    const unsigned short* __restrict__ wp, const float* __restrict__ proj_b,
    const float* __restrict__ bias_pad) {
    __shared__ __align__(16) unsigned char smem[140288];
    unsigned short* regA = (unsigned short*)smem;             // xln / attn_out
    unsigned short* regB = (unsigned short*)(smem + 36864);   // q|k rows
    unsigned short* vT   = (unsigned short*)(smem + 103424);  // 256 x 72

    const int tid = threadIdx.x;
    const int lane = tid & 63;
    const int wid = tid >> 6;          // 0..15
    const int l15 = lane & 15;
    const int lg = lane >> 4;
    const int u = blockIdx.x;
    const int NV = IS_RSA ? 64 : 50;
    const f32x4 fzero = {0.f, 0.f, 0.f, 0.f};

    int reg_off = 0, xb = 0, wi = 0, wj = 0;
    if (!IS_RSA) {
        reg_off = ((u & 31) * 64 + (u >> 5)) * 256;
        xb = u >> 6;
        int xn = u & 63;
        wi = xn >> 3; wj = xn & 7;
    }

    // ---- phase 1: gather + layernorm -> regA bf16 (zero the pad rows) ----
    for (int r = wid; r < 64; r += 16) {
        if (r < NV) {
            const float* src;
            if (IS_RSA) src = reg_tok + (u * 64 + r) * 256;
            else if (r == 0) src = reg2_in + reg_off;
            else {
                int p = r - 1;
                src = x + (xb * 3136 + (wi * 7 + p / 7) * 56 + (wj * 7 + p % 7)) * 256;
            }
            f32x4 v = *(const f32x4*)(src + lane * 4);
            float s = v[0] + v[1] + v[2] + v[3];
            float s2 = v[0] * v[0] + v[1] * v[1] + v[2] * v[2] + v[3] * v[3];
            #pragma unroll
            for (int m = 1; m < 64; m <<= 1) { s += __shfl_xor(s, m); s2 += __shfl_xor(s2, m); }
            float mean = s * 0.00390625f;
            float rstd = rsqrtf(s2 * 0.00390625f - mean * mean + 1e-5f);
            u16x4 o;
            #pragma unroll
            for (int j = 0; j < 4; ++j) {
                int c = lane * 4 + j;
                o[j] = f2bf((v[j] - mean) * rstd * ln_g[c] + ln_b[c]);
            }
            *(u16x4*)(regA + r * 264 + lane * 4) = o;
        } else {
            u16x4 z = {0, 0, 0, 0};
            *(u16x4*)(regA + r * 264 + lane * 4) = z;
        }
    }
    __syncthreads();

    const int h = wid >> 1;
    const int qb = (wid & 1) * 32;

    // ---- phase 2: qkv = xln @ wq^T + b; q,k -> regB rows; v -> vT transposed ----
    {
        f32x4 acc[4][3];
        #pragma unroll
        for (int mi = 0; mi < 4; ++mi)
            #pragma unroll
            for (int t = 0; t < 3; ++t) acc[mi][t] = fzero;
        #pragma unroll
        for (int ks = 0; ks < 8; ++ks) {
            int k = ks * 32 + lg * 8;
            bf16x8 a[4], b[3];
            #pragma unroll
            for (int mi = 0; mi < 4; ++mi) a[mi] = *(const bf16x8*)(regA + (mi * 16 + l15) * 264 + k);
            #pragma unroll
            for (int t = 0; t < 3; ++t) b[t] = *(const bf16x8*)(wq + (wid * 48 + t * 16 + l15) * 256 + k);
            #pragma unroll
            for (int mi = 0; mi < 4; ++mi)
                #pragma unroll
                for (int t = 0; t < 3; ++t)
                    acc[mi][t] = __builtin_amdgcn_mfma_f32_16x16x32_bf16(a[mi], b[t], acc[mi][t], 0, 0, 0);
        }
        #pragma unroll
        for (int mi = 0; mi < 4; ++mi)
            #pragma unroll
            for (int t = 0; t < 3; ++t) {
                int col = wid * 48 + t * 16 + l15;
                float bias = qkv_b[col];
                #pragma unroll
                for (int r = 0; r < 4; ++r) {
                    int row = mi * 16 + lg * 4 + r;
                    unsigned short hv = f2bf(acc[mi][t][r] + bias);
                    if (col < 512) regB[row * 520 + col] = hv;
                    else vT[(col - 512) * 72 + row] = hv;
                }
            }
    }

    // prefetch relative-position bias (8 x f32x4) before the barrier
    f32x4 bv[4][2];
    if (!IS_RSA) {
        #pragma unroll
        for (int mi = 0; mi < 4; ++mi)
            #pragma unroll
            for (int nj = 0; nj < 2; ++nj)
                bv[mi][nj] = *(const f32x4*)(bias_pad + h * 4096 + (qb + nj * 16 + l15) * 64 + mi * 16 + lg * 4);
    }
    __syncthreads();

    // ---- phase 3: swapped attention. S^T[k][q] = sum_d K[k][d] Q[q][d] ----
    f32x4 st[4][2];
    {
        int k0 = h * 32 + lg * 8;
        bf16x8 af[4], bfq[2];
        #pragma unroll
        for (int mi = 0; mi < 4; ++mi) af[mi] = *(const bf16x8*)(regB + (mi * 16 + l15) * 520 + 256 + k0);
        #pragma unroll
        for (int nj = 0; nj < 2; ++nj) bfq[nj] = *(const bf16x8*)(regB + (qb + nj * 16 + l15) * 520 + k0);
        #pragma unroll
        for (int mi = 0; mi < 4; ++mi)
            #pragma unroll
            for (int nj = 0; nj < 2; ++nj)
                st[mi][nj] = __builtin_amdgcn_mfma_f32_16x16x32_bf16(af[mi], bfq[nj], fzero, 0, 0, 0);
    }

    // softmax over k (rows of S^T); lane l15 = q-col, k spread over (mi, lg, r)
    u16x4 pf[4][2];  // packed bf16 P^T fragment (low 4 k-slots)
    #pragma unroll
    for (int nj = 0; nj < 2; ++nj) {
        float ps[4][4];
        float mx = -3.0e38f;
        #pragma unroll
        for (int mi = 0; mi < 4; ++mi)
            #pragma unroll
            for (int r = 0; r < 4; ++r) {
                float t = st[mi][nj][r] * SCALE_Q;
                if (!IS_RSA) t += bv[mi][nj][r];
                ps[mi][r] = t;
                mx = fmaxf(mx, t);
            }
        mx = fmaxf(mx, __shfl_xor(mx, 16));
        mx = fmaxf(mx, __shfl_xor(mx, 32));
        float sum = 0.f;
        #pragma unroll
        for (int mi = 0; mi < 4; ++mi)
            #pragma unroll
            for (int r = 0; r < 4; ++r) { ps[mi][r] = __expf(ps[mi][r] - mx); sum += ps[mi][r]; }
        sum += __shfl_xor(sum, 16);
        sum += __shfl_xor(sum, 32);
        float inv = __builtin_amdgcn_rcpf(sum);
        #pragma unroll
        for (int mi = 0; mi < 4; ++mi) {
            u16x4 p4;
            #pragma unroll
            for (int r = 0; r < 4; ++r) p4[r] = f2bf(ps[mi][r] * inv);
            pf[mi][nj] = p4;
        }
    }

    // PV via K=16-emulated 16x16x32 MFMA: O^T[d][q] += V^T-frag * P^T-frag
    f32x4 ov[2][2];
    #pragma unroll
    for (int m2 = 0; m2 < 2; ++m2) { ov[m2][0] = fzero; ov[m2][1] = fzero; }
    #pragma unroll
    for (int kt = 0; kt < 4; ++kt) {
        bf16x8 pb[2];
        #pragma unroll
        for (int nj = 0; nj < 2; ++nj) {
            bf16x8 t;
            t[0] = (short)pf[kt][nj][0]; t[1] = (short)pf[kt][nj][1];
            t[2] = (short)pf[kt][nj][2]; t[3] = (short)pf[kt][nj][3];
            t[4] = 0; t[5] = 0; t[6] = 0; t[7] = 0;
            pb[nj] = t;
        }
        #pragma unroll
        for (int m2 = 0; m2 < 2; ++m2) {
            u16x4 av = *(const u16x4*)(vT + (h * 32 + m2 * 16 + l15) * 72 + kt * 16 + lg * 4);
            bf16x8 a8;
            a8[0] = (short)av[0]; a8[1] = (short)av[1]; a8[2] = (short)av[2]; a8[3] = (short)av[3];
            a8[4] = 0; a8[5] = 0; a8[6] = 0; a8[7] = 0;
            #pragma unroll
            for (int nj = 0; nj < 2; ++nj)
                ov[m2][nj] = __builtin_amdgcn_mfma_f32_16x16x32_bf16(a8, pb[nj], ov[m2][nj], 0, 0, 0);
        }
    }
    // attn_out: row q = qb+nj*16+l15, cols h*32+m2*16+lg*4+r -> vector u16x4
    #pragma unroll
    for (int m2 = 0; m2 < 2; ++m2)
        #pragma unroll
        for (int nj = 0; nj < 2; ++nj) {
            u16x4 o4;
            #pragma unroll
            for (int r = 0; r < 4; ++r) o4[r] = f2bf(ov[m2][nj][r]);
            *(u16x4*)(regA + (qb + nj * 16 + l15) * 264 + h * 32 + m2 * 16 + lg * 4) = o4;
        }
    __syncthreads();

    // ---- phase 4: proj + bias + residual, scatter to destination ----
    {
        int nb = wid * 16;
        f32x4 acc[4];
        #pragma unroll
        for (int mi = 0; mi < 4; ++mi) acc[mi] = fzero;
        #pragma unroll
        for (int ks = 0; ks < 8; ++ks) {
            int k = ks * 32 + lg * 8;
            bf16x8 a[4], b;
            #pragma unroll
            for (int mi = 0; mi < 4; ++mi) a[mi] = *(const bf16x8*)(regA + (mi * 16 + l15) * 264 + k);
            b = *(const bf16x8*)(wp + (nb + l15) * 256 + k);
            #pragma unroll
            for (int mi = 0; mi < 4; ++mi)
                acc[mi] = __builtin_amdgcn_mfma_f32_16x16x32_bf16(a[mi], b, acc[mi], 0, 0, 0);
        }
        int col = nb + l15;
        float pb = proj_b[col];
        #pragma unroll
        for (int mi = 0; mi < 4; ++mi)
            #pragma unroll
            for (int r = 0; r < 4; ++r) {
                int row = mi * 16 + lg * 4 + r;
                if (row < NV) {
                    float val = acc[mi][r] + pb;
                    if (IS_RSA) {
                        int off = (u * 64 + row) * 256 + col;
                        out[off] = val + reg_tok[off];
                    } else if (row == 0) {
                        out[reg_off + col] = val + reg2_in[reg_off + col];
                    } else {
                        int p = row - 1;
                        int off = (xb * 3136 + (wi * 7 + p / 7) * 56 + (wj * 7 + p % 7)) * 256 + col;
                        out[524288 + off] = val + x[off];
                    }
                }
            }
    }
}

// ---------------------------------------------------------------------------
// Fused MLP over the dense t-matrix (d_out): 64 rows / 512 threads (8 waves).
// (round-9 bench form — global best: dbuf hld, one __syncthreads per chunk)
// ---------------------------------------------------------------------------
__global__ __launch_bounds__(512, 4) void mlp_kernel(
    float* __restrict__ dout,
    const float* __restrict__ ln_g, const float* __restrict__ ln_b,
    const unsigned short* __restrict__ w1, const float* __restrict__ b1,
    const unsigned short* __restrict__ w2, const float* __restrict__ b2) {
    __shared__ __align__(16) unsigned short xst[64 * 264];
    __shared__ __align__(16) unsigned short hld[2][64 * 136];
    const int tid = threadIdx.x;
    const int lane = tid & 63;
    const int wid = tid >> 6;          // 0..7
    const int l15 = lane & 15;
    const int lg = lane >> 4;
    const int row0 = blockIdx.x * 64;
    const f32x4 fzero = {0.f, 0.f, 0.f, 0.f};

    // ---- LN: 8 rows per wave -> xst (once) ----
    #pragma unroll
    for (int i = 0; i < 8; ++i) {
        int r = wid * 8 + i;
        f32x4 v = *(const f32x4*)(dout + (row0 + r) * 256 + lane * 4);
        float s = v[0] + v[1] + v[2] + v[3];
        float s2 = v[0] * v[0] + v[1] * v[1] + v[2] * v[2] + v[3] * v[3];
        #pragma unroll
        for (int m = 1; m < 64; m <<= 1) { s += __shfl_xor(s, m); s2 += __shfl_xor(s2, m); }
        float mean = s * 0.00390625f;
        float rstd = rsqrtf(s2 * 0.00390625f - mean * mean + 1e-5f);
        u16x4 o;
        #pragma unroll
        for (int j = 0; j < 4; ++j) {
            int c = lane * 4 + j;
            o[j] = f2bf((v[j] - mean) * rstd * ln_g[c] + ln_b[c]);
        }
        *(u16x4*)(xst + r * 264 + lane * 4) = o;
    }

    // ---- prefetch chunk-0 weight fragments (32 + 32 VGPRs) ----
    bf16x8 w1f[8], w2f[8];
    #pragma unroll
    for (int ks = 0; ks < 8; ++ks)
        w1f[ks] = *(const bf16x8*)(w1 + (wid * 16 + l15) * 256 + ks * 32 + lg * 8);
    #pragma unroll
    for (int ks = 0; ks < 4; ++ks)
        #pragma unroll
        for (int ni = 0; ni < 2; ++ni)
            w2f[ks * 2 + ni] = *(const bf16x8*)(w2 + (wid * 32 + ni * 16 + l15) * 1024 + ks * 32 + lg * 8);
    __syncthreads();

    f32x4 acc2[4][2];
    #pragma unroll
    for (int mi = 0; mi < 4; ++mi) { acc2[mi][0] = fzero; acc2[mi][1] = fzero; }

    #pragma unroll
    for (int c = 0; c < 8; ++c) {
        unsigned short* hb = &hld[c & 1][0];
        // ---- fc1: A from xst (LDS), B = prefetched w1f ----
        f32x4 acc1[4];
        #pragma unroll
        for (int mi = 0; mi < 4; ++mi) acc1[mi] = fzero;
        #pragma unroll
        for (int ks = 0; ks < 8; ++ks) {
            int k = ks * 32 + lg * 8;
            bf16x8 a[4];
            #pragma unroll
            for (int mi = 0; mi < 4; ++mi)
                a[mi] = *(const bf16x8*)(xst + (mi * 16 + l15) * 264 + k);
            #pragma unroll
            for (int mi = 0; mi < 4; ++mi)
                acc1[mi] = __builtin_amdgcn_mfma_f32_16x16x32_bf16(a[mi], w1f[ks], acc1[mi], 0, 0, 0);
        }
        // issue next-chunk w1 loads NOW (in flight across GELU + barrier + fc2)
        if (c < 7) {
            #pragma unroll
            for (int ks = 0; ks < 8; ++ks)
                w1f[ks] = *(const bf16x8*)(w1 + ((c + 1) * 128 + wid * 16 + l15) * 256 + ks * 32 + lg * 8);
        }
        // ---- GELU -> hld[c&1] ----
        {
            int hc = wid * 16 + l15;
            float bb = b1[c * 128 + hc];
            #pragma unroll
            for (int mi = 0; mi < 4; ++mi)
                #pragma unroll
                for (int r = 0; r < 4; ++r)
                    hb[(mi * 16 + lg * 4 + r) * 136 + hc] = f2bf(gelu_fast(acc1[mi][r] + bb));
        }
        __syncthreads();  // the ONLY barrier per chunk (hld double-buffered)
        // ---- fc2: A from hld (LDS), B = prefetched w2f; accumulate ----
        #pragma unroll
        for (int ks = 0; ks < 4; ++ks) {
            int k = ks * 32 + lg * 8;
            bf16x8 a[4];
            #pragma unroll
            for (int mi = 0; mi < 4; ++mi)
                a[mi] = *(const bf16x8*)(hb + (mi * 16 + l15) * 136 + k);
            #pragma unroll
            for (int mi = 0; mi < 4; ++mi)
                #pragma unroll
                for (int ni = 0; ni < 2; ++ni)
                    acc2[mi][ni] = __builtin_amdgcn_mfma_f32_16x16x32_bf16(a[mi], w2f[ks * 2 + ni], acc2[mi][ni], 0, 0, 0);
        }
        // issue next-chunk w2 loads NOW (in flight across next fc1 + barrier)
        if (c < 7) {
            #pragma unroll
            for (int ks = 0; ks < 4; ++ks)
                #pragma unroll
                for (int ni = 0; ni < 2; ++ni)
                    w2f[ks * 2 + ni] = *(const bf16x8*)(w2 + (wid * 32 + ni * 16 + l15) * 1024 + (c + 1) * 128 + ks * 32 + lg * 8);
        }
    }
    #pragma unroll
    for (int mi = 0; mi < 4; ++mi)
        #pragma unroll
        for (int ni = 0; ni < 2; ++ni) {
            int col = wid * 32 + ni * 16 + l15;
            float bb = b2[col];
            #pragma unroll
            for (int r = 0; r < 4; ++r) {
                int row = row0 + mi * 16 + lg * 4 + r;
                float* dst = dout + row * 256 + col;
                *dst = acc2[mi][ni][r] + bb + *dst;
            }
        }
}

// ---------------------------------------------------------------------------
extern "C" void kernel_launch(void* const* d_in, const int* in_sizes, int n_in,
                              void* d_out, int out_size, void* d_ws, size_t ws_size,
                              hipStream_t stream) {
    const float* regional = (const float*)d_in[0];
    const float* x = (const float*)d_in[1];
    const float* n1g = (const float*)d_in[2];
    const float* n1b = (const float*)d_in[3];
    const float* n2g = (const float*)d_in[4];
    const float* n2b = (const float*)d_in[5];
    const float* n3g = (const float*)d_in[6];
    const float* n3b = (const float*)d_in[7];
    const float* qkvw = (const float*)d_in[8];
    const float* qkvb = (const float*)d_in[9];
    const float* projw = (const float*)d_in[10];
    const float* projb = (const float*)d_in[11];
    const float* btab = (const float*)d_in[12];
    const float* f1w = (const float*)d_in[13];
    const float* f1b = (const float*)d_in[14];
    const float* f2w = (const float*)d_in[15];
    const float* f2b = (const float*)d_in[16];
    const int* relidx = (const int*)d_in[17];

    unsigned char* ws = (unsigned char*)d_ws;
    unsigned short* wq = (unsigned short*)(ws);            // 768*256  bf16
    unsigned short* wp = (unsigned short*)(ws + 393216);   // 256*256  bf16
    unsigned short* w1 = (unsigned short*)(ws + 524288);   // 1024*256 bf16
    unsigned short* w2 = (unsigned short*)(ws + 1048576);  // 256*1024 bf16
    float* bias_pad    = (float*)(ws + 1572864);           // 8*64*64 f32
    float* reg2        = (float*)(ws + 1703936);           // 32*64*256 f32

    float* out = (float*)d_out;

    prep_kernel<<<512, 256, 0, stream>>>(qkvw, projw, f1w, f2w, btab, relidx, wq, wp, w1, w2, bias_pad);
    attn_kernel<1><<<32, 1024, 0, stream>>>(regional, x, nullptr, reg2, n1g, n1b, wq, qkvb, wp, projb, nullptr);
    attn_kernel<0><<<2048, 1024, 0, stream>>>(regional, x, reg2, out, n2g, n2b, wq, qkvb, wp, projb, bias_pad);
    mlp_kernel<<<1600, 512, 0, stream>>>(out, n3g, n3b, w1, f1b, w2, f2b);
}